// Round 2
// baseline (1143.790 us; speedup 1.0000x reference)
//
#include <hip/hip_runtime.h>

// LSTM: SEQ=4096, BATCH=4096, IN=2, HID=8, fp32.
// R2: 16 lanes per batch element; ALL cross-lane traffic via DPP (VALU pipe),
// zero LDS in the loop. Lane (q = l&3, u = l>>2) owns gate rows q*8+u and
// q*8+u+4 (2 full dot products, no matvec redundancy).
//   gate exchange: quad_perm xor{1,2,3}  (intra-quad: 4 gates of unit u)
//   h all-gather : xor{4,8,12} = (half_mirror+quad_xor3), ror8 compositions
// 4096/4-elems-per-wave = 1024 waves = 1 wave/SIMD: issue-bound, not
// latency-bound (the old 2x LDS round trips were the 572-cyc/step chain).

#define SEQ   4096
#define BATCH 4096
#define PF    4

#define DPP_QX1  0xB1   // quad_perm [1,0,3,2]  = lane ^ 1
#define DPP_QX2  0x4E   // quad_perm [2,3,0,1]  = lane ^ 2
#define DPP_QX3  0x1B   // quad_perm [3,2,1,0]  = lane ^ 3
#define DPP_ROR8 0x128  // row_ror:8            = lane ^ 8 (within 16-row)
#define DPP_HMIR 0x141  // row_half_mirror      = lane ^ 7

template<int CTRL>
__device__ __forceinline__ float dppf(float v) {
    int i = __builtin_bit_cast(int, v);
    int r = __builtin_amdgcn_update_dpp(i, i, CTRL, 0xf, 0xf, false);
    return __builtin_bit_cast(float, r);
}
__device__ __forceinline__ float xor4f(float v) {   // lane ^ 4 = (^7)^3
    return dppf<DPP_QX3>(dppf<DPP_HMIR>(v));
}
__device__ __forceinline__ float xor8f(float v) { return dppf<DPP_ROR8>(v); }

__global__ __launch_bounds__(256, 1) void lstm_kernel(
    const float* __restrict__ x,    // (SEQ, BATCH, 2)
    const float* __restrict__ h0,   // (1, BATCH, 8)
    const float* __restrict__ c0,   // (1, BATCH, 8)
    const float* __restrict__ Wih,  // (32, 2)
    const float* __restrict__ Whh,  // (32, 8)
    const float* __restrict__ bih,  // (32)
    const float* __restrict__ bhh,  // (32)
    float* __restrict__ out)        // (1, BATCH, 8)
{
    const int tid = threadIdx.x;
    const int l   = tid & 15;        // lane within 16-lane group (DPP row half)
    const int q   = l & 3;           // gate: 0=i 1=f 2=g~ 3=o
    const int u   = l >> 2;          // unit-pair index: owns units u and u+4
    const int b   = blockIdx.x * 16 + (tid >> 4);

    const int gA = q * 8 + u;        // gate row for unit u
    const int gB = gA + 4;           // gate row for unit u+4

    // Whh rows in u-relative (gather) order: slot m holds coeff for h_{u^m}(+4)
    float wAl[4], wAh[4], wBl[4], wBh[4];
#pragma unroll
    for (int m = 0; m < 4; ++m) {
        const int k = u ^ m;
        wAl[m] = Whh[gA * 8 + k];
        wAh[m] = Whh[gA * 8 + 4 + k];
        wBl[m] = Whh[gB * 8 + k];
        wBh[m] = Whh[gB * 8 + 4 + k];
    }
    const float wxA0 = Wih[2 * gA], wxA1 = Wih[2 * gA + 1];
    const float wxB0 = Wih[2 * gB], wxB1 = Wih[2 * gB + 1];
    const float biasA = bih[gA] + bhh[gA];
    const float biasB = bih[gB] + bhh[gB];

    // activation constants (rows A,B share gate type q)
    const float LOG2E = 1.4426950408889634f;
    const float tm    = (q == 2) ? 2.0f : 1.0f;
    const float addc  = 1.0f - tm;
    const float smul  = -LOG2E * tm;
    const float cmul  = -2.0f * LOG2E;

    const bool q1 = (q & 1) != 0;    // hoisted to v_cmp outside loop
    const bool q2 = (q & 2) != 0;

    // state (replicated across the 4 q-lanes of each quad)
    float cA = c0[b * 8 + u];
    float cB = c0[b * 8 + u + 4];
    float hA = h0[b * 8 + u];
    float hB = h0[b * 8 + u + 4];

    const float2* xp = (const float2*)x + b;   // xp[s*BATCH]
    float2 xb[PF];
#pragma unroll
    for (int p = 0; p < PF; ++p) xb[p] = xp[(size_t)p * BATCH];

    for (int s = 0; s < SEQ; s += PF) {
#pragma unroll
        for (int p = 0; p < PF; ++p) {
            const float2 xc = xb[p];
            int sn = s + p + PF;
            sn = (sn < SEQ) ? sn : (SEQ - 1);
            xb[p] = xp[(size_t)sn * BATCH];

            // ---- h all-gather via DPP: hL[m] = h_{u^m}, hH[m] = h_{u^m+4}
            const float hL0 = hA;
            const float hL1 = xor4f(hA);
            const float hL2 = xor8f(hA);
            const float hL3 = xor8f(hL1);       // ^12 = ^8 of ^4
            const float hH0 = hB;
            const float hH1 = xor4f(hB);
            const float hH2 = xor8f(hB);
            const float hH3 = xor8f(hH1);

            // ---- 2 full gate-row dot products (2 accumulators each)
            float a0 = __builtin_fmaf(xc.x, wxA0, biasA);
            a0 = __builtin_fmaf(xc.y, wxA1, a0);
            float a1 = hL1 * wAl[1];
            a0 = __builtin_fmaf(hL0, wAl[0], a0);
            a1 = __builtin_fmaf(hL2, wAl[2], a1);
            a0 = __builtin_fmaf(hL3, wAl[3], a0);
            a1 = __builtin_fmaf(hH0, wAh[0], a1);
            a0 = __builtin_fmaf(hH1, wAh[1], a0);
            a1 = __builtin_fmaf(hH2, wAh[2], a1);
            a0 = __builtin_fmaf(hH3, wAh[3], a0);
            const float preA = a0 + a1;

            float b0 = __builtin_fmaf(xc.x, wxB0, biasB);
            b0 = __builtin_fmaf(xc.y, wxB1, b0);
            float b1 = hL1 * wBl[1];
            b0 = __builtin_fmaf(hL0, wBl[0], b0);
            b1 = __builtin_fmaf(hL2, wBl[2], b1);
            b0 = __builtin_fmaf(hL3, wBl[3], b0);
            b1 = __builtin_fmaf(hH0, wBh[0], b1);
            b0 = __builtin_fmaf(hH1, wBh[1], b0);
            b1 = __builtin_fmaf(hH2, wBh[2], b1);
            b0 = __builtin_fmaf(hH3, wBh[3], b0);
            const float preB = b0 + b1;

            // ---- activation (sigmoid or tanh by gate type)
            const float eA  = __builtin_amdgcn_exp2f(preA * smul);
            const float actA = __builtin_fmaf(__builtin_amdgcn_rcpf(eA + 1.0f), tm, addc);
            const float eB  = __builtin_amdgcn_exp2f(preB * smul);
            const float actB = __builtin_fmaf(__builtin_amdgcn_rcpf(eB + 1.0f), tm, addc);

            // ---- gate exchange: A_k = gate (q^k) of unit u (quad_perm)
            const float A1 = dppf<DPP_QX1>(actA);
            const float A2 = dppf<DPP_QX2>(actA);
            const float A3 = dppf<DPP_QX3>(actA);
            const float B1 = dppf<DPP_QX1>(actB);
            const float B2 = dppf<DPP_QX2>(actB);
            const float B3 = dppf<DPP_QX3>(actB);

            // role selection: i = A_q, f = A_{1^q}, g~ = A_{2^q}, o = A_{3^q}
            const float igA = q1 ? (A1 * A3) : (actA * A2);
            const float s1A = q1 ? actA : A1;
            const float s3A = q1 ? A2 : A3;
            const float fA  = q2 ? s3A : s1A;
            const float oA  = q2 ? s1A : s3A;

            const float igB = q1 ? (B1 * B3) : (actB * B2);
            const float s1B = q1 ? actB : B1;
            const float s3B = q1 ? B2 : B3;
            const float fB  = q2 ? s3B : s1B;
            const float oB  = q2 ? s1B : s3B;

            // ---- c/h update (redundant across the 4 q-lanes of the quad)
            cA = __builtin_fmaf(fA, cA, igA);
            const float e2A = __builtin_amdgcn_exp2f(cA * cmul);
            const float thA = __builtin_fmaf(__builtin_amdgcn_rcpf(e2A + 1.0f), 2.0f, -1.0f);
            hA = oA * thA;

            cB = __builtin_fmaf(fB, cB, igB);
            const float e2B = __builtin_amdgcn_exp2f(cB * cmul);
            const float thB = __builtin_fmaf(__builtin_amdgcn_rcpf(e2B + 1.0f), 2.0f, -1.0f);
            hB = oB * thB;
        }
    }

    if (q == 0) {
        out[b * 8 + u]     = hA;
        out[b * 8 + u + 4] = hB;
    }
}

extern "C" void kernel_launch(void* const* d_in, const int* in_sizes, int n_in,
                              void* d_out, int out_size, void* d_ws, size_t ws_size,
                              hipStream_t stream) {
    const float* x   = (const float*)d_in[0];
    const float* h0  = (const float*)d_in[1];
    const float* c0  = (const float*)d_in[2];
    const float* Wih = (const float*)d_in[3];
    const float* Whh = (const float*)d_in[4];
    const float* bih = (const float*)d_in[5];
    const float* bhh = (const float*)d_in[6];
    float* out = (float*)d_out;

    dim3 grid(BATCH / 16);   // 256 blocks -> 1 block/CU, 4 waves -> 4 SIMDs
    dim3 block(256);         // 16 groups of 16 lanes
    hipLaunchKernelGGL(lstm_kernel, grid, block, 0, stream,
                       x, h0, c0, Wih, Whh, bih, bhh, out);
}

// Round 4
// 943.002 us; speedup vs baseline: 1.2129x; 1.2129x over previous
//
#include <hip/hip_runtime.h>

// LSTM: SEQ=4096, BATCH=4096, IN=2, HID=8, fp32.
// R4: L=16 lanes/elem (q=l&3 gate, u=l>>2 unit-pair). Packed fp32 pairs
// (lo=unit u, hi=unit u+4) via COMPILER-generated v_pk ops (<2 x float>
// arithmetic) -- no inline asm (R3's NaN: asm is opaque to the DPP hazard
// recognizer / VGPR-pair alignment). NEW: gate exchange via quad_perm
// BROADCAST (0x00/0x55/0xAA/0xFF): every lane gets i,f,g~,o of its unit in
// 8 DPP with zero cndmask role-selection. 1024 waves = 1/SIMD.

#define SEQ   4096
#define BATCH 4096
#define PF    8

#define DPP_QX3   0x1B  // quad_perm [3,2,1,0] = lane ^ 3
#define DPP_ROR8  0x128 // row_ror:8           = lane ^ 8 (within 16-row)
#define DPP_HMIR  0x141 // row_half_mirror     = lane ^ 7
#define DPP_BC0   0x00  // quad_perm [0,0,0,0] -> gate i
#define DPP_BC1   0x55  // quad_perm [1,1,1,1] -> gate f
#define DPP_BC2   0xAA  // quad_perm [2,2,2,2] -> gate g~
#define DPP_BC3   0xFF  // quad_perm [3,3,3,3] -> gate o

typedef float v2f __attribute__((ext_vector_type(2)));

template<int CTRL>
__device__ __forceinline__ float dppf(float v) {
    int i = __builtin_bit_cast(int, v);
    int r = __builtin_amdgcn_update_dpp(i, i, CTRL, 0xf, 0xf, false);
    return __builtin_bit_cast(float, r);
}
template<int CTRL>
__device__ __forceinline__ v2f dpp2(v2f v) {
    v2f r; r.x = dppf<CTRL>(v.x); r.y = dppf<CTRL>(v.y); return r;
}
__device__ __forceinline__ v2f xor4v(v2f v) {   // lane ^ 4 = (^7)^3
    return dpp2<DPP_QX3>(dpp2<DPP_HMIR>(v));
}
__device__ __forceinline__ v2f xor8v(v2f v) { return dpp2<DPP_ROR8>(v); }

__device__ __forceinline__ v2f vfma(v2f a, v2f b, v2f c) {
    return __builtin_elementwise_fma(a, b, c);
}

__global__ __launch_bounds__(256, 1) void lstm_kernel(
    const float* __restrict__ x,    // (SEQ, BATCH, 2)
    const float* __restrict__ h0,   // (1, BATCH, 8)
    const float* __restrict__ c0,   // (1, BATCH, 8)
    const float* __restrict__ Wih,  // (32, 2)
    const float* __restrict__ Whh,  // (32, 8)
    const float* __restrict__ bih,  // (32)
    const float* __restrict__ bhh,  // (32)
    float* __restrict__ out)        // (1, BATCH, 8)
{
    const int tid = threadIdx.x;
    const int l   = tid & 15;        // lane in 16-lane group
    const int q   = l & 3;           // gate: 0=i 1=f 2=g~ 3=o (quad lane)
    const int u   = l >> 2;          // unit-pair: owns units u and u+4
    const int b   = blockIdx.x * 16 + (tid >> 4);

    const int gA = q * 8 + u;        // gate row, unit u
    const int gB = gA + 4;           // gate row, unit u+4

    // Whh packed pairs in gather (xor-m) order:
    // WA[m] = (Whh[gA][u^m], Whh[gA][(u^m)+4]), WB same for row gB.
    v2f WA[4], WB[4];
#pragma unroll
    for (int m = 0; m < 4; ++m) {
        const int k = u ^ m;
        WA[m].x = Whh[gA * 8 + k];
        WA[m].y = Whh[gA * 8 + 4 + k];
        WB[m].x = Whh[gB * 8 + k];
        WB[m].y = Whh[gB * 8 + 4 + k];
    }
    const float wxA0 = Wih[2 * gA], wxA1 = Wih[2 * gA + 1];
    const float wxB0 = Wih[2 * gB], wxB1 = Wih[2 * gB + 1];
    const float biasA = bih[gA] + bhh[gA];
    const float biasB = bih[gB] + bhh[gB];

    // activation constants: lanes' rows A,B share gate type q.
    // sigmoid(p)=1/(1+exp2(-p*log2e)); tanh(p)=2*sigmoid(2p)-1.
    const float LOG2E = 1.4426950408889634f;
    const float tm    = (q == 2) ? 2.0f : 1.0f;
    const v2f tmP   = { tm, tm };
    const v2f addcP = { 1.0f - tm, 1.0f - tm };
    const v2f smulP = { -LOG2E * tm, -LOG2E * tm };
    const v2f cmulP = { -2.0f * LOG2E, -2.0f * LOG2E };
    const v2f oneP  = { 1.0f, 1.0f };
    const v2f twoP  = { 2.0f, 2.0f };
    const v2f nonP  = { -1.0f, -1.0f };

    // state pairs (lo = unit u, hi = unit u+4), replicated across q-lanes
    v2f cP = { c0[b * 8 + u], c0[b * 8 + u + 4] };
    v2f hP = { h0[b * 8 + u], h0[b * 8 + u + 4] };

    const float2* __restrict__ xp2 = (const float2*)x;
    float2 xb[PF];
#pragma unroll
    for (int p = 0; p < PF; ++p) xb[p] = xp2[p * BATCH + b];

    for (int s = 0; s < SEQ; s += PF) {
#pragma unroll
        for (int p = 0; p < PF; ++p) {
            const float2 xc = xb[p];
            const int sn  = (s + p + PF) & (SEQ - 1);   // uniform wrap
            xb[p] = xp2[sn * BATCH + b];

            // ---- h all-gather (pairs): P[m] = (h_{u^m}, h_{u^m+4})
            const v2f P0 = hP;
            const v2f P1 = xor4v(hP);
            const v2f P2 = xor8v(hP);
            const v2f P3 = xor8v(P1);

            // ---- two gate-row dot products, packed halves
            v2f accA = { __builtin_fmaf(xc.x, wxA0, biasA), xc.y * wxA1 };
            accA = vfma(P0, WA[0], accA);
            accA = vfma(P1, WA[1], accA);
            accA = vfma(P2, WA[2], accA);
            accA = vfma(P3, WA[3], accA);

            v2f accB = { __builtin_fmaf(xc.x, wxB0, biasB), xc.y * wxB1 };
            accB = vfma(P0, WB[0], accB);
            accB = vfma(P1, WB[1], accB);
            accB = vfma(P2, WB[2], accB);
            accB = vfma(P3, WB[3], accB);

            const v2f pre = { accA.x + accA.y, accB.x + accB.y };

            // ---- activation (sigmoid/tanh by lane's gate type)
            const v2f t = pre * smulP;
            v2f e; e.x = __builtin_amdgcn_exp2f(t.x);
                   e.y = __builtin_amdgcn_exp2f(t.y);
            const v2f d = e + oneP;
            v2f r; r.x = __builtin_amdgcn_rcpf(d.x);
                   r.y = __builtin_amdgcn_rcpf(d.y);
            const v2f act = vfma(r, tmP, addcP);   // (actA, actB)

            // ---- gate exchange: quad_perm BROADCAST, no selection needed.
            // act lane q holds gate-q rows for (u, u+4); broadcast each.
            const v2f gi = dpp2<DPP_BC0>(act);
            const v2f gf = dpp2<DPP_BC1>(act);
            const v2f gg = dpp2<DPP_BC2>(act);
            const v2f go = dpp2<DPP_BC3>(act);

            // ---- c/h update (packed; redundant across the 4 q-lanes)
            cP = vfma(gf, cP, gi * gg);
            const v2f t2 = cP * cmulP;
            v2f e2; e2.x = __builtin_amdgcn_exp2f(t2.x);
                    e2.y = __builtin_amdgcn_exp2f(t2.y);
            const v2f d2 = e2 + oneP;
            v2f r2; r2.x = __builtin_amdgcn_rcpf(d2.x);
                    r2.y = __builtin_amdgcn_rcpf(d2.y);
            const v2f th = vfma(r2, twoP, nonP);
            hP = go * th;
        }
    }

    if (q == 0) {
        out[b * 8 + u]     = hP.x;
        out[b * 8 + u + 4] = hP.y;
    }
}

extern "C" void kernel_launch(void* const* d_in, const int* in_sizes, int n_in,
                              void* d_out, int out_size, void* d_ws, size_t ws_size,
                              hipStream_t stream) {
    const float* x   = (const float*)d_in[0];
    const float* h0  = (const float*)d_in[1];
    const float* c0  = (const float*)d_in[2];
    const float* Wih = (const float*)d_in[3];
    const float* Whh = (const float*)d_in[4];
    const float* bih = (const float*)d_in[5];
    const float* bhh = (const float*)d_in[6];
    float* out = (float*)d_out;

    dim3 grid(BATCH / 16);   // 256 blocks
    dim3 block(256);         // 16 groups of 16 lanes; 1024 waves = 1/SIMD
    hipLaunchKernelGGL(lstm_kernel, grid, block, 0, stream,
                       x, h0, c0, Wih, Whh, bih, bhh, out);
}